// Round 7
// baseline (555.030 us; speedup 1.0000x reference)
//
#include <hip/hip_runtime.h>

#define BB 32
#define LL 2048
#define DD 512
#define DFFN 256
#define NBLK 6
#define NCHUNK 64
#define CHUNK 32             // L per chunk
#define NTHR 256
#define FTHR 1024
#define EPSV 1e-6f

typedef float v4f __attribute__((ext_vector_type(4)));

__device__ __forceinline__ float bflo(unsigned u){ return __uint_as_float(u << 16); }
__device__ __forceinline__ float bfhi(unsigned u){ return __uint_as_float(u & 0xFFFF0000u); }
__device__ __forceinline__ unsigned pack2bf(float lo, float hi){
  unsigned a = __float_as_uint(lo); a += 0x7FFFu + ((a >> 16) & 1u);   // RNE
  unsigned b = __float_as_uint(hi); b += 0x7FFFu + ((b >> 16) & 1u);
  return (a >> 16) | (b & 0xFFFF0000u);
}

// block-wide sum over 1024 threads (16 waves)
__device__ __forceinline__ float blk_sum16(float v, volatile float* red){
  #pragma unroll
  for (int o = 32; o > 0; o >>= 1) v += __shfl_xor(v, o, 64);
  if ((threadIdx.x & 63) == 0) red[threadIdx.x >> 6] = v;
  __syncthreads();
  float r = 0.f;
  #pragma unroll
  for (int i = 0; i < 16; ++i) r += red[i];
  __syncthreads();
  return r;
}

// ---------------- idx0 attention fused with fp32->bf16 K/V pack (CHUNK=32) ----------------
__global__ __launch_bounds__(NTHR)
void k_att_first(const float* __restrict__ kin,
                 const float* __restrict__ vin,
                 const float* __restrict__ qin,
                 unsigned* __restrict__ kbf,
                 unsigned* __restrict__ vbf,
                 float* __restrict__ eplane,
                 float* __restrict__ Zc,
                 float* __restrict__ partialA) {
  const int tid  = threadIdx.x;
  const int bid  = blockIdx.x;
  const int b    = bid >> 6;
  const int c    = bid & 63;
  const int l0   = c * CHUNK;
  const int wave = tid >> 6;
  const int lane = tid & 63;

  __shared__ __align__(16) float q_lds[DD];
  __shared__ float s_lds[CHUNK];
  __shared__ __align__(16) float pa_lds[4*DD];

  q_lds[tid]       = qin[b*DD + tid];
  q_lds[tid + 256] = qin[b*DD + tid + 256];
  __syncthreads();

  const float scale = 0.04419417382415922f;  // 1/sqrt(512)
  const int rg = lane >> 3;   // 8 rows per wave
  const int j  = lane & 7;    // 8 lanes per row
  {
    const int lrow = wave*8 + rg;                     // 0..31
    const float* krow = kin + ((size_t)b*LL + l0 + lrow)*DD;
    unsigned*   krowb = kbf + ((size_t)b*LL + l0 + lrow)*(DD/2);
    float acc = 0.f;
    #pragma unroll
    for (int it = 0; it < 8; ++it) {
      v4f fa = __builtin_nontemporal_load((const v4f*)(krow + it*64 + j*8));
      v4f fb = __builtin_nontemporal_load((const v4f*)(krow + it*64 + j*8 + 4));
      const float4* qv = (const float4*)&q_lds[it*64 + j*8];
      float4 qa = qv[0], qb = qv[1];
      acc += fa.x*qa.x + fa.y*qa.y + fa.z*qa.z + fa.w*qa.w
           + fb.x*qb.x + fb.y*qb.y + fb.z*qb.z + fb.w*qb.w;
      uint4 o;
      o.x = pack2bf(fa.x, fa.y); o.y = pack2bf(fa.z, fa.w);
      o.z = pack2bf(fb.x, fb.y); o.w = pack2bf(fb.z, fb.w);
      *((uint4*)(krowb + it*32 + j*4)) = o;
    }
    acc += __shfl_xor(acc, 1, 64);
    acc += __shfl_xor(acc, 2, 64);
    acc += __shfl_xor(acc, 4, 64);
    if (j == 0) {
      float e = __expf(acc * scale);
      s_lds[lrow] = e;
      eplane[(size_t)b*LL + l0 + lrow] = e;
    }
  }
  __syncthreads();

  if (wave == 0) {
    float z = (lane < CHUNK) ? s_lds[lane] : 0.f;
    #pragma unroll
    for (int o = 32; o > 0; o >>= 1) z += __shfl_xor(z, o, 64);
    if (lane == 0) Zc[b*NCHUNK + c] = z;
  }

  // partial e@V from fp32 V, packing bf16 V on the way (8 rows per wave)
  float a0=0,a1=0,a2=0,a3=0,a4=0,a5=0,a6=0,a7=0;
  const float* vbase = vin + ((size_t)b*LL + l0 + wave*8)*DD + lane*8;
  unsigned*    vbfb  = vbf + ((size_t)b*LL + l0 + wave*8)*(DD/2) + lane*4;
  #pragma unroll
  for (int r = 0; r < 8; ++r) {
    float p = s_lds[wave*8 + r];
    v4f f0 = __builtin_nontemporal_load((const v4f*)(vbase + (size_t)r*DD));
    v4f f1 = __builtin_nontemporal_load((const v4f*)(vbase + (size_t)r*DD + 4));
    a0 += p*f0.x; a1 += p*f0.y; a2 += p*f0.z; a3 += p*f0.w;
    a4 += p*f1.x; a5 += p*f1.y; a6 += p*f1.z; a7 += p*f1.w;
    uint4 o;
    o.x = pack2bf(f0.x, f0.y); o.y = pack2bf(f0.z, f0.w);
    o.z = pack2bf(f1.x, f1.y); o.w = pack2bf(f1.z, f1.w);
    *((uint4*)(vbfb + (size_t)r*(DD/2))) = o;
  }
  {
    float4* pw = (float4*)&pa_lds[wave*DD + lane*8];
    pw[0] = make_float4(a0,a1,a2,a3);
    pw[1] = make_float4(a4,a5,a6,a7);
  }
  __syncthreads();
  {
    float r0 = pa_lds[tid]     + pa_lds[DD+tid]     + pa_lds[2*DD+tid]     + pa_lds[3*DD+tid];
    float r1 = pa_lds[tid+256] + pa_lds[DD+tid+256] + pa_lds[2*DD+tid+256] + pa_lds[3*DD+tid+256];
    partialA[((size_t)b*NCHUNK + c)*DD + tid]       = r0;
    partialA[((size_t)b*NCHUNK + c)*DD + tid + 256] = r1;
  }
}

// ---------------- idx>=1 attention: bf16 K/V (CHUNK=32) ----------------
__global__ __launch_bounds__(NTHR)
void k_att(const unsigned short* __restrict__ kbf,
           const unsigned short* __restrict__ vbf,
           const float* __restrict__ q_cur,
           float* __restrict__ eplane,
           float* __restrict__ Zc,
           float* __restrict__ partialA) {
  const int tid  = threadIdx.x;
  const int bid  = blockIdx.x;
  const int b    = bid >> 6;
  const int c    = bid & 63;
  const int l0   = c * CHUNK;
  const int wave = tid >> 6;
  const int lane = tid & 63;

  __shared__ __align__(16) float q_lds[DD];
  __shared__ float s_lds[CHUNK];
  __shared__ __align__(16) float pa_lds[4*DD];

  q_lds[tid]       = q_cur[b*DD + tid];
  q_lds[tid + 256] = q_cur[b*DD + tid + 256];
  __syncthreads();

  const float scale = 0.04419417382415922f;
  const int rg = lane >> 3;
  const int j  = lane & 7;
  {
    const int lrow = wave*8 + rg;                     // 0..31
    const unsigned* krow = (const unsigned*)(kbf + ((size_t)b*LL + l0 + lrow)*DD);
    float acc = 0.f;
    #pragma unroll
    for (int it = 0; it < 8; ++it) {
      uint4 kv = *((const uint4*)(krow + it*32 + j*4));
      const float4* qv = (const float4*)&q_lds[it*64 + j*8];
      float4 qa = qv[0], qb = qv[1];
      acc += bflo(kv.x)*qa.x + bfhi(kv.x)*qa.y
           + bflo(kv.y)*qa.z + bfhi(kv.y)*qa.w
           + bflo(kv.z)*qb.x + bfhi(kv.z)*qb.y
           + bflo(kv.w)*qb.z + bfhi(kv.w)*qb.w;
    }
    acc += __shfl_xor(acc, 1, 64);
    acc += __shfl_xor(acc, 2, 64);
    acc += __shfl_xor(acc, 4, 64);
    if (j == 0) {
      float e = __expf(acc * scale);
      s_lds[lrow] = e;
      eplane[(size_t)b*LL + l0 + lrow] = e;
    }
  }
  __syncthreads();

  if (wave == 0) {
    float z = (lane < CHUNK) ? s_lds[lane] : 0.f;
    #pragma unroll
    for (int o = 32; o > 0; o >>= 1) z += __shfl_xor(z, o, 64);
    if (lane == 0) Zc[b*NCHUNK + c] = z;
  }

  float a0=0,a1=0,a2=0,a3=0,a4=0,a5=0,a6=0,a7=0;
  const unsigned* vbase = (const unsigned*)(vbf + ((size_t)b*LL + l0 + wave*8)*DD) + lane*4;
  #pragma unroll
  for (int r = 0; r < 8; ++r) {
    float p = s_lds[wave*8 + r];
    uint4 vv = *((const uint4*)(vbase + (size_t)r*(DD/2)));
    a0 += p*bflo(vv.x); a1 += p*bfhi(vv.x);
    a2 += p*bflo(vv.y); a3 += p*bfhi(vv.y);
    a4 += p*bflo(vv.z); a5 += p*bfhi(vv.z);
    a6 += p*bflo(vv.w); a7 += p*bfhi(vv.w);
  }
  {
    float4* pw = (float4*)&pa_lds[wave*DD + lane*8];
    pw[0] = make_float4(a0,a1,a2,a3);
    pw[1] = make_float4(a4,a5,a6,a7);
  }
  __syncthreads();
  {
    float r0 = pa_lds[tid]     + pa_lds[DD+tid]     + pa_lds[2*DD+tid]     + pa_lds[3*DD+tid];
    float r1 = pa_lds[tid+256] + pa_lds[DD+tid+256] + pa_lds[2*DD+tid+256] + pa_lds[3*DD+tid+256];
    partialA[((size_t)b*NCHUNK + c)*DD + tid]       = r0;
    partialA[((size_t)b*NCHUNK + c)*DD + tid + 256] = r1;
  }
}

// ---------------- combine + norm1 + FFN + norm2; 1024 thr, one block per batch row ----------------
__global__ __launch_bounds__(FTHR)
void k_ffn(const float* __restrict__ Zc,
           const float* __restrict__ partialA,
           const float* __restrict__ qsrc,     // qin for idx0, q_cur after
           float* __restrict__ q_cur,
           const float* __restrict__ W1,
           const float* __restrict__ b1,
           const float* __restrict__ W2,
           const float* __restrict__ b2,
           const float* __restrict__ al1,
           const float* __restrict__ bi1,
           const float* __restrict__ al2,
           const float* __restrict__ bi2,
           float* __restrict__ out,
           float* __restrict__ Zinv_buf,
           int idx) {
  const int tid = threadIdx.x;
  const int b   = blockIdx.x;

  __shared__ __align__(16) float a_lds[DD];
  __shared__ float h_lds[DFFN];
  __shared__ float stage[1024];
  __shared__ float red[16];
  __shared__ float ZZ;

  if (tid < 64) {
    float z = Zc[b*NCHUNK + tid];
    #pragma unroll
    for (int o = 32; o > 0; o >>= 1) z += __shfl_xor(z, o, 64);
    if (tid == 0) { float zi = 1.f / z; ZZ = zi; Zinv_buf[idx*BB + b] = zi; }
  }
  __syncthreads();
  const float zinv = ZZ;

  // x = q + (sum_c Atilde_c)/Z  (threads 0..511 hold one d each)
  float x = 0.f;
  if (tid < DD) {
    float sA = 0.f;
    #pragma unroll 8
    for (int cc = 0; cc < NCHUNK; ++cc)
      sA += partialA[((size_t)b*NCHUNK + cc)*DD + tid];
    x = qsrc[b*DD + tid] + sA * zinv;
  }
  float s  = blk_sum16(x, red);
  float mu = s * (1.f/512.f);
  float d  = (tid < DD) ? (x - mu) : 0.f;
  float vs = blk_sum16(d*d, red);
  float rstd = 1.f / (sqrtf(vs * (1.f/511.f)) + EPSV);   // ddof=1, (std+eps)
  if (tid < DD)
    a_lds[tid] = al1[idx*DD + tid] * (d*rstd) + bi1[idx*DD + tid];
  __syncthreads();

  // FF1: 4-way split over d; f = tid&255, seg = tid>>8
  {
    const int f   = tid & 255;
    const int seg = tid >> 8;
    const float* w1p = W1 + (size_t)idx*DD*DFFN + f;
    const int d0 = seg*128;
    float f0=0,f1=0,f2=0,f3=0;
    #pragma unroll 8
    for (int dd = d0; dd < d0+128; dd += 4) {
      f0 += a_lds[dd+0]*w1p[(size_t)(dd+0)*DFFN];
      f1 += a_lds[dd+1]*w1p[(size_t)(dd+1)*DFFN];
      f2 += a_lds[dd+2]*w1p[(size_t)(dd+2)*DFFN];
      f3 += a_lds[dd+3]*w1p[(size_t)(dd+3)*DFFN];
    }
    stage[seg*256 + f] = (f0+f1)+(f2+f3);
  }
  __syncthreads();
  if (tid < DFFN) {
    float hv = stage[tid] + stage[256+tid] + stage[512+tid] + stage[768+tid]
             + b1[idx*DFFN + tid];
    h_lds[tid] = fmaxf(hv, 0.f);
  }
  __syncthreads();

  // FF2: 2-way split over jj; dout = tid&511, seg2 = tid>>9
  {
    const int dout = tid & 511;
    const int seg2 = tid >> 9;
    const float* w2p = W2 + (size_t)idx*DFFN*DD + dout;
    const int j0 = seg2*128;
    float f0=0,f1=0,f2=0,f3=0;
    #pragma unroll 8
    for (int jj = j0; jj < j0+128; jj += 4) {
      f0 += h_lds[jj+0]*w2p[(size_t)(jj+0)*DD];
      f1 += h_lds[jj+1]*w2p[(size_t)(jj+1)*DD];
      f2 += h_lds[jj+2]*w2p[(size_t)(jj+2)*DD];
      f3 += h_lds[jj+3]*w2p[(size_t)(jj+3)*DD];
    }
    stage[seg2*512 + dout] = (f0+f1)+(f2+f3);
  }
  __syncthreads();

  float y = 0.f;
  if (tid < DD)
    y = a_lds[tid] + stage[tid] + stage[512+tid] + b2[idx*DD + tid];
  float s2  = blk_sum16(y, red);
  float mu2 = s2 * (1.f/512.f);
  float e   = (tid < DD) ? (y - mu2) : 0.f;
  float vs2 = blk_sum16(e*e, red);
  float rstd2 = 1.f / (sqrtf(vs2 * (1.f/511.f)) + EPSV);
  if (tid < DD) {
    float qn = al2[idx*DD + tid] * (e*rstd2) + bi2[idx*DD + tid];
    q_cur[b*DD + tid] = qn;
    if (idx == 2)      out[b*1024 + tid]       = qn;
    else if (idx == 5) out[b*1024 + 512 + tid] = qn;
  }
}

// ---------------- wout: all 6 planes at once, thread per (b,l) ----------------
__global__ __launch_bounds__(NTHR)
void k_wout(const float* __restrict__ eall,       // (6, B, L)
            const float* __restrict__ Zinv_buf,   // (6, B)
            float* __restrict__ wout) {           // (B, L, 6)
  const int g = blockIdx.x * NTHR + threadIdx.x;  // 0..65535
  const int b = g >> 11;
  const int l = g & 2047;
  float p[6];
  #pragma unroll
  for (int i = 0; i < 6; ++i)
    p[i] = eall[((size_t)i*BB + b)*LL + l] * Zinv_buf[i*BB + b];
  float* w = wout + (size_t)g*6;
  *((float2*)(w + 0)) = make_float2(p[0], p[1]);
  *((float2*)(w + 2)) = make_float2(p[2], p[3]);
  *((float2*)(w + 4)) = make_float2(p[4], p[5]);
}

extern "C" void kernel_launch(void* const* d_in, const int* in_sizes, int n_in,
                              void* d_out, int out_size, void* d_ws, size_t ws_size,
                              hipStream_t stream) {
  const float* qin = (const float*)d_in[0];
  const float* kin = (const float*)d_in[1];
  const float* vin = (const float*)d_in[2];
  const float* W1  = (const float*)d_in[3];
  const float* b1  = (const float*)d_in[4];
  const float* W2  = (const float*)d_in[5];
  const float* b2  = (const float*)d_in[6];
  const float* al1 = (const float*)d_in[7];
  const float* bi1 = (const float*)d_in[8];
  const float* al2 = (const float*)d_in[9];
  const float* bi2 = (const float*)d_in[10];
  float* out  = (float*)d_out;
  float* wout = out + BB*2*DD;      // softmax-weights region: (B, L, 6) fp32

  unsigned short* kbf = (unsigned short*)d_ws;
  unsigned short* vbf = kbf + (size_t)BB*LL*DD;
  float* fws      = (float*)(vbf + (size_t)BB*LL*DD);
  float* q_cur    = fws;                          // BB*DD
  float* Zc       = q_cur + BB*DD;                // BB*NCHUNK
  float* Zinv_buf = Zc + BB*NCHUNK;               // NBLK*BB
  float* eall     = Zinv_buf + NBLK*BB;           // NBLK*BB*LL
  float* partialA = eall + (size_t)NBLK*BB*LL;    // BB*NCHUNK*DD

  for (int idx = 0; idx < NBLK; ++idx) {
    if (idx == 0) {
      k_att_first<<<dim3(BB*NCHUNK), dim3(NTHR), 0, stream>>>(
          kin, vin, qin, (unsigned*)kbf, (unsigned*)vbf,
          eall, Zc, partialA);
    } else {
      k_att<<<dim3(BB*NCHUNK), dim3(NTHR), 0, stream>>>(
          kbf, vbf, q_cur, eall + (size_t)idx*BB*LL, Zc, partialA);
    }
    const float* qsrc = (idx == 0) ? qin : q_cur;
    k_ffn<<<dim3(BB), dim3(FTHR), 0, stream>>>(Zc, partialA, qsrc, q_cur,
                                               W1, b1, W2, b2, al1, bi1, al2, bi2,
                                               out, Zinv_buf, idx);
  }
  k_wout<<<dim3(BB*LL/NTHR), dim3(NTHR), 0, stream>>>(eall, Zinv_buf, wout);
}